// Round 2
// 658.655 us; speedup vs baseline: 1.0344x; 1.0344x over previous
//
#include <hip/hip_runtime.h>
#include <stdint.h>
#include <stddef.h>

// Problem constants (fixed by the reference)
#define N_TOT  8192   // rows of adj / rows of x
#define D_FEAT 256    // feature dim
// Main-kernel tile config
#define BM 32         // rows per block
#define BK 64         // k per iteration
#define LDK 72        // padded LDS row stride (bf16 elems); 144 B = 16B-aligned rows
#define K_ITERS (N_TOT / BK)   // 128

typedef float f32x4_t __attribute__((ext_vector_type(4)));
typedef short s16x8_t __attribute__((ext_vector_type(8)));

// fp32 -> bf16 round-to-nearest-even (inputs finite)
__device__ __forceinline__ unsigned short f2bf(float f) {
    union { float f; unsigned int u; } a;
    a.f = f;
    unsigned int r = a.u + 0x7FFFu + ((a.u >> 16) & 1u);
    return (unsigned short)(r >> 16);
}

// streamed (read-once) load of adj: nontemporal so it doesn't evict L2-resident xT
__device__ __forceinline__ f32x4_t ldg_nt(const float* p) {
    return __builtin_nontemporal_load((const f32x4_t*)p);
}

// ---------------------------------------------------------------------------
// Pre-kernel: xT[n][k] = bf16(x[k][n]).  x: [8192][256] fp32 -> xT: [256][8192] bf16
// ---------------------------------------------------------------------------
__global__ __launch_bounds__(256) void xpose_kernel(
    const float* __restrict__ x, unsigned short* __restrict__ xT)
{
    __shared__ unsigned short T[64 * 72];   // [n][k] tile, stride 72 -> 16B-aligned rows
    const int t  = threadIdx.x;
    const int k0 = blockIdx.x * 64;
    const int n0 = blockIdx.y * 64;

    #pragma unroll
    for (int i = 0; i < 4; ++i) {
        const int kr = (t >> 4) + 16 * i;
        const int c4 = (t & 15) * 4;
        float4 v = *(const float4*)(x + (size_t)(k0 + kr) * D_FEAT + n0 + c4);
        T[(c4 + 0) * 72 + kr] = f2bf(v.x);
        T[(c4 + 1) * 72 + kr] = f2bf(v.y);
        T[(c4 + 2) * 72 + kr] = f2bf(v.z);
        T[(c4 + 3) * 72 + kr] = f2bf(v.w);
    }
    __syncthreads();
    #pragma unroll
    for (int i = 0; i < 2; ++i) {
        const int n  = (t >> 3) + 32 * i;
        const int c8 = (t & 7) * 8;
        uint4 w = *(const uint4*)&T[n * 72 + c8];
        *(uint4*)(xT + (size_t)(n0 + n) * N_TOT + k0 + c8) = w;
    }
}

// ---------------------------------------------------------------------------
// Main kernel: out[m, g*256 + n] = sum_k adj_g[m,k] * x[k,n]
// Block: 512 thr = 8 waves; wave w owns cols [32w, 32w+32).  BM=32 rows.
//
// Pipeline: double-buffered LDS A-tile, ONE raw s_barrier per K-step
// (lgkmcnt(0) only — no vmcnt drain). A register-prefetched 2 iterations
// deep (tile it+3 issued at iter it), B 1 deep; compiler emits counted
// vmcnt before each use so HBM loads stay in flight across barriers.
// ---------------------------------------------------------------------------
__global__ __launch_bounds__(512, 4) void h2gcn_kernel(
    const float* __restrict__ adj0,
    const float* __restrict__ adj1,
    const unsigned short* __restrict__ xT,
    float* __restrict__ out)
{
    const int g  = blockIdx.y;
    const float* __restrict__ adj = g ? adj1 : adj0;
    const int m0   = blockIdx.x * BM;
    const int t    = threadIdx.x;
    const int lane = t & 63;
    const int w    = t >> 6;      // wave 0..7
    const int fl   = lane & 15;   // fragment row/col
    const int fq   = lane >> 4;   // fragment quad

    __shared__ __align__(16) unsigned short Asm[2][BM * LDK];  // 2 x 4608 B

    // A staging: thread -> (row, 4-wide k chunk); one float4 per thread
    const int a_row = t >> 4;          // 0..31
    const int a_c4  = (t & 15) * 4;    // 0..60
    const float* aBase = adj + (size_t)(m0 + a_row) * N_TOT + a_c4;

    // B fragment addresses: row n = 32w + 16nt + fl of xT
    const unsigned short* bBase0 = xT + (size_t)(32 * w + fl) * N_TOT + 8 * fq;
    const unsigned short* bBase1 = bBase0 + (size_t)16 * N_TOT;

    f32x4_t aR[2];          // A prefetch ring: slot (T+1)&1 holds tile T
    s16x8_t bR[2][2][2];    // [slot][nt][ks], slot it&1 holds B tile it
    f32x4_t acc[2][2];

    #pragma unroll
    for (int mt = 0; mt < 2; ++mt)
        #pragma unroll
        for (int nt = 0; nt < 2; ++nt) {
            f32x4_t z = {0.0f, 0.0f, 0.0f, 0.0f};
            acc[mt][nt] = z;
        }

    // ---- prologue: issue tiles 0,1,2 of A and tile 0 of B; stage tile 0 ----
    f32x4_t a0 = ldg_nt(aBase);             // tile 0
    aR[1]      = ldg_nt(aBase + BK);        // tile 1 (staged at iter 0)
    aR[0]      = ldg_nt(aBase + 2 * BK);    // tile 2 (staged at iter 1)
    #pragma unroll
    for (int ks = 0; ks < 2; ++ks) {
        bR[0][0][ks] = *(const s16x8_t*)(bBase0 + 32 * ks);
        bR[0][1][ks] = *(const s16x8_t*)(bBase1 + 32 * ks);
    }
    {
        ushort4 v;
        v.x = f2bf(a0.x); v.y = f2bf(a0.y);
        v.z = f2bf(a0.z); v.w = f2bf(a0.w);
        *(ushort4*)&Asm[0][a_row * LDK + a_c4] = v;
    }
    __syncthreads();   // one-time full drain in prologue is fine

    // ---- main loop: one raw barrier per K-step, no vmcnt drain ----
    #pragma unroll 2
    for (int it = 0; it < K_ITERS; ++it) {
        const int cur = it & 1;
        const int nxt = cur ^ 1;

        // stage tile it+1 into LDS[nxt] (aR[nxt] was issued at iter it-2;
        // compiler inserts a counted vmcnt before the converts)
        {
            ushort4 v;
            v.x = f2bf(aR[nxt].x); v.y = f2bf(aR[nxt].y);
            v.z = f2bf(aR[nxt].z); v.w = f2bf(aR[nxt].w);
            *(ushort4*)&Asm[nxt][a_row * LDK + a_c4] = v;
        }

        // A fragments of tile it from LDS[cur]
        s16x8_t af[2][2];
        #pragma unroll
        for (int mt = 0; mt < 2; ++mt)
            #pragma unroll
            for (int ks = 0; ks < 2; ++ks)
                af[mt][ks] = *(const s16x8_t*)&Asm[cur][(16 * mt + fl) * LDK + 32 * ks + 8 * fq];

        // prefetch: A tile it+3 (2 iterations in flight), B tile it+1
        const int ta = (it + 3 < K_ITERS) ? (it + 3) : (K_ITERS - 1);
        const int tb = (it + 1 < K_ITERS) ? (it + 1) : (K_ITERS - 1);
        const size_t ka = (size_t)ta * BK;
        const size_t kb = (size_t)tb * BK;
        aR[nxt] = ldg_nt(aBase + ka);
        #pragma unroll
        for (int ks = 0; ks < 2; ++ks) {
            bR[nxt][0][ks] = *(const s16x8_t*)(bBase0 + kb + 32 * ks);
            bR[nxt][1][ks] = *(const s16x8_t*)(bBase1 + kb + 32 * ks);
        }

        // LDS visibility only: my stage-writes landed, my af reads complete.
        // Global prefetches above remain in flight across the barrier.
        asm volatile("s_waitcnt lgkmcnt(0)" ::: "memory");
        __builtin_amdgcn_sched_barrier(0);
        __builtin_amdgcn_s_barrier();

        #pragma unroll
        for (int ks = 0; ks < 2; ++ks)
            #pragma unroll
            for (int mt = 0; mt < 2; ++mt)
                #pragma unroll
                for (int nt = 0; nt < 2; ++nt)
                    acc[mt][nt] = __builtin_amdgcn_mfma_f32_16x16x32_bf16(
                        af[mt][ks], bR[cur][nt][ks], acc[mt][nt], 0, 0, 0);
    }

    // epilogue: C/D layout col=lane&15, row=(lane>>4)*4+reg
    #pragma unroll
    for (int mt = 0; mt < 2; ++mt)
        #pragma unroll
        for (int nt = 0; nt < 2; ++nt)
            #pragma unroll
            for (int r = 0; r < 4; ++r) {
                const int row = m0 + 16 * mt + 4 * fq + r;
                const int col = g * D_FEAT + 32 * w + 16 * nt + fl;
                out[(size_t)row * (2 * D_FEAT) + col] = acc[mt][nt][r];
            }
}

extern "C" void kernel_launch(void* const* d_in, const int* in_sizes, int n_in,
                              void* d_out, int out_size, void* d_ws, size_t ws_size,
                              hipStream_t stream) {
    const float* x      = (const float*)d_in[0];
    const float* adj_t  = (const float*)d_in[1];
    const float* adj_t2 = (const float*)d_in[2];
    float* out = (float*)d_out;
    unsigned short* xT = (unsigned short*)d_ws;   // 256*8192 bf16 = 4 MiB
    (void)in_sizes; (void)n_in; (void)out_size; (void)ws_size;

    // 1) transpose+convert x -> xT (bf16, [n][k])
    hipLaunchKernelGGL(xpose_kernel, dim3(N_TOT / 64, D_FEAT / 64), dim3(256), 0, stream, x, xT);
    // 2) fused dual GEMM. 256 m-tiles x 2 matrices = 512 blocks (2/CU, 16 waves/CU)
    hipLaunchKernelGGL(h2gcn_kernel, dim3(N_TOT / BM, 2), dim3(512), 0, stream,
                       adj_t, adj_t2, xT, out);
}

// Round 3
// 569.604 us; speedup vs baseline: 1.1961x; 1.1563x over previous
//
#include <hip/hip_runtime.h>
#include <stdint.h>
#include <stddef.h>

// Problem constants (fixed by the reference)
#define N_TOT  8192   // rows of adj / rows of x
#define D_FEAT 256    // feature dim
// Main-kernel tile config
#define BM 32         // rows per block
#define BK 64         // k per iteration
#define K_ITERS (N_TOT / BK)   // 128

typedef float f32x4_t __attribute__((ext_vector_type(4)));
typedef short s16x8_t __attribute__((ext_vector_type(8)));

// fp32 -> bf16 round-to-nearest-even (inputs finite)
__device__ __forceinline__ unsigned short f2bf(float f) {
    union { float f; unsigned int u; } a;
    a.f = f;
    unsigned int r = a.u + 0x7FFFu + ((a.u >> 16) & 1u);
    return (unsigned short)(r >> 16);
}

struct f32x8 { f32x4_t lo, hi; };
// streamed (read-once) 32B load of adj: nontemporal so it doesn't evict xT
__device__ __forceinline__ f32x8 ld8_nt(const float* p) {
    f32x8 v;
    v.lo = __builtin_nontemporal_load((const f32x4_t*)p);
    v.hi = __builtin_nontemporal_load((const f32x4_t*)(p + 4));
    return v;
}

// ---------------------------------------------------------------------------
// Pre-kernel: xT[n][k] = bf16(x[k][n]).  x: [8192][256] fp32 -> xT: [256][8192] bf16
// ---------------------------------------------------------------------------
__global__ __launch_bounds__(256) void xpose_kernel(
    const float* __restrict__ x, unsigned short* __restrict__ xT)
{
    __shared__ unsigned short T[64 * 72];   // [n][k] tile, stride 72 -> 16B-aligned rows
    const int t  = threadIdx.x;
    const int k0 = blockIdx.x * 64;
    const int n0 = blockIdx.y * 64;

    #pragma unroll
    for (int i = 0; i < 4; ++i) {
        const int kr = (t >> 4) + 16 * i;
        const int c4 = (t & 15) * 4;
        float4 v = *(const float4*)(x + (size_t)(k0 + kr) * D_FEAT + n0 + c4);
        T[(c4 + 0) * 72 + kr] = f2bf(v.x);
        T[(c4 + 1) * 72 + kr] = f2bf(v.y);
        T[(c4 + 2) * 72 + kr] = f2bf(v.z);
        T[(c4 + 3) * 72 + kr] = f2bf(v.w);
    }
    __syncthreads();
    #pragma unroll
    for (int i = 0; i < 2; ++i) {
        const int n  = (t >> 3) + 32 * i;
        const int c8 = (t & 7) * 8;
        uint4 w = *(const uint4*)&T[n * 72 + c8];
        *(uint4*)(xT + (size_t)(n0 + n) * N_TOT + k0 + c8) = w;
    }
}

// ---------------------------------------------------------------------------
// Main kernel (FUSED g): out[m, g*256 + n] = sum_k adj_g[m,k] * x[k,n] for g=0,1
// Grid: 256 blocks (1/CU) x 512 thr (8 waves). Wave w owns cols [32w,32w+32)
// of BOTH g-halves (B fragments shared across g -> B L2/L3 traffic halved).
//
// LDS: granule-major, XOR-swizzled. One granule = 16 B = 8 bf16 =
// A_g[16*mt+fl][32*ks+8*fq .. +8]. Slot(g,mt,ks,fq,fl) =
//   ((g*2+mt)*2+ks)*64 + fq*16 + ((fl ^ (4*ks+fq)) & 15)
// -> af ds_read_b128: 8 consecutive lanes hit 8 distinct bank-quads (free);
// -> staging ds_write_b128: the 8 (ks,fq) combos at fixed fl hit 8 distinct
//    quads (free). Replaces the old LDK=72 layout (8-way conflict, 8.4M cyc).
//
// Pipeline: one raw s_barrier + lgkmcnt(0) per K-step (no vmcnt drain);
// A register-prefetched 2 deep (tile it+3 issued at iter it), B 1 deep.
// Staging split: waves 0-3 stage A0 granules, waves 4-7 stage A1.
// ---------------------------------------------------------------------------
__global__ __launch_bounds__(512, 2) void h2gcn_kernel(
    const float* __restrict__ adj0,
    const float* __restrict__ adj1,
    const unsigned short* __restrict__ xT,
    float* __restrict__ out)
{
    const int m0   = blockIdx.x * BM;
    const int t    = threadIdx.x;
    const int lane = t & 63;
    const int w    = t >> 6;      // wave 0..7
    const int fl   = lane & 15;   // fragment row/col
    const int fq   = lane >> 4;   // fragment quad

    __shared__ __align__(16) unsigned short Asm[2][512 * 8];  // 2 x 8 KiB

    // ---- staging map: thread -> one 32B granule of A_{gsel}, tile column c_w
    const int gsel = t >> 8;              // 0: adj0 (waves 0-3), 1: adj1 (waves 4-7)
    const int r_l  = ((t >> 6) & 3) * 8 + ((t >> 3) & 7);   // row 0..31
    const int c_w  = t & 7;               // granule col (8 floats each)
    const int ks_w = c_w >> 2, fq_w = c_w & 3;
    const int mt_w = r_l >> 4,  fl_w = r_l & 15;
    const int wslot = ((gsel * 2 + mt_w) * 2 + ks_w) * 64 + fq_w * 16
                    + ((fl_w ^ (4 * ks_w + fq_w)) & 15);
    const float* aBase = (gsel ? adj1 : adj0)
                       + (size_t)(m0 + r_l) * N_TOT + c_w * 8;

    // ---- B fragment addresses: xT row n = 32w + 16nt + fl, k-offset 8fq
    const unsigned short* bBase0 = xT + (size_t)(32 * w + fl) * N_TOT + 8 * fq;
    const unsigned short* bBase1 = bBase0 + (size_t)16 * N_TOT;

    f32x8   aR[2];          // A prefetch ring: slot (T+1)&1 holds tile T
    s16x8_t bR[2][2][2];    // [slot][nt][ks], slot it&1 holds B tile it
    f32x4_t acc[2][2][2];   // [g][mt][nt]

    #pragma unroll
    for (int g = 0; g < 2; ++g)
        #pragma unroll
        for (int mt = 0; mt < 2; ++mt)
            #pragma unroll
            for (int nt = 0; nt < 2; ++nt) {
                f32x4_t z = {0.0f, 0.0f, 0.0f, 0.0f};
                acc[g][mt][nt] = z;
            }

    // ---- prologue: issue A tiles 0,1,2 and B tile 0; stage tile 0 ----
    f32x8 a0 = ld8_nt(aBase);               // tile 0
    aR[1]    = ld8_nt(aBase + BK);          // tile 1 (staged at iter 0)
    aR[0]    = ld8_nt(aBase + 2 * BK);      // tile 2 (staged at iter 1)
    #pragma unroll
    for (int ks = 0; ks < 2; ++ks) {
        bR[0][0][ks] = *(const s16x8_t*)(bBase0 + 32 * ks);
        bR[0][1][ks] = *(const s16x8_t*)(bBase1 + 32 * ks);
    }
    {
        s16x8_t pk;
        pk[0] = (short)f2bf(a0.lo.x); pk[1] = (short)f2bf(a0.lo.y);
        pk[2] = (short)f2bf(a0.lo.z); pk[3] = (short)f2bf(a0.lo.w);
        pk[4] = (short)f2bf(a0.hi.x); pk[5] = (short)f2bf(a0.hi.y);
        pk[6] = (short)f2bf(a0.hi.z); pk[7] = (short)f2bf(a0.hi.w);
        *(s16x8_t*)&Asm[0][wslot * 8] = pk;
    }
    __syncthreads();   // one-time full drain in prologue is fine

    // ---- main loop: one raw barrier per K-step, no vmcnt drain ----
    #pragma unroll 2
    for (int it = 0; it < K_ITERS; ++it) {
        const int cur = it & 1;
        const int nxt = cur ^ 1;

        // stage tile it+1 into LDS[nxt] (aR[nxt] issued at iter it-2;
        // compiler inserts a counted vmcnt before the converts)
        {
            s16x8_t pk;
            pk[0] = (short)f2bf(aR[nxt].lo.x); pk[1] = (short)f2bf(aR[nxt].lo.y);
            pk[2] = (short)f2bf(aR[nxt].lo.z); pk[3] = (short)f2bf(aR[nxt].lo.w);
            pk[4] = (short)f2bf(aR[nxt].hi.x); pk[5] = (short)f2bf(aR[nxt].hi.y);
            pk[6] = (short)f2bf(aR[nxt].hi.z); pk[7] = (short)f2bf(aR[nxt].hi.w);
            *(s16x8_t*)&Asm[nxt][wslot * 8] = pk;
        }

        // A fragments of tile it (both g) from LDS[cur]
        s16x8_t af[2][2][2];   // [g][mt][ks]
        #pragma unroll
        for (int g = 0; g < 2; ++g)
            #pragma unroll
            for (int mt = 0; mt < 2; ++mt)
                #pragma unroll
                for (int ks = 0; ks < 2; ++ks) {
                    const int slot = ((g * 2 + mt) * 2 + ks) * 64 + fq * 16
                                   + ((fl ^ (4 * ks + fq)) & 15);
                    af[g][mt][ks] = *(const s16x8_t*)&Asm[cur][slot * 8];
                }

        // prefetch: A tile it+3 (2 deep), B tile it+1 (1 deep)
        const int ta = (it + 3 < K_ITERS) ? (it + 3) : (K_ITERS - 1);
        const int tb = (it + 1 < K_ITERS) ? (it + 1) : (K_ITERS - 1);
        aR[nxt] = ld8_nt(aBase + (size_t)ta * BK);
        const size_t kb = (size_t)tb * BK;
        #pragma unroll
        for (int ks = 0; ks < 2; ++ks) {
            bR[nxt][0][ks] = *(const s16x8_t*)(bBase0 + kb + 32 * ks);
            bR[nxt][1][ks] = *(const s16x8_t*)(bBase1 + kb + 32 * ks);
        }

        // LDS visibility only: stage-writes landed, af reads complete.
        // Global prefetches above stay in flight across the barrier.
        asm volatile("s_waitcnt lgkmcnt(0)" ::: "memory");
        __builtin_amdgcn_sched_barrier(0);
        __builtin_amdgcn_s_barrier();

        #pragma unroll
        for (int ks = 0; ks < 2; ++ks)
            #pragma unroll
            for (int g = 0; g < 2; ++g)
                #pragma unroll
                for (int mt = 0; mt < 2; ++mt)
                    #pragma unroll
                    for (int nt = 0; nt < 2; ++nt)
                        acc[g][mt][nt] = __builtin_amdgcn_mfma_f32_16x16x32_bf16(
                            af[g][mt][ks], bR[cur][nt][ks], acc[g][mt][nt], 0, 0, 0);
    }

    // epilogue: C/D layout col=lane&15, row=(lane>>4)*4+reg; streamed stores
    #pragma unroll
    for (int g = 0; g < 2; ++g)
        #pragma unroll
        for (int mt = 0; mt < 2; ++mt)
            #pragma unroll
            for (int nt = 0; nt < 2; ++nt)
                #pragma unroll
                for (int r = 0; r < 4; ++r) {
                    const int row = m0 + 16 * mt + 4 * fq + r;
                    const int col = g * D_FEAT + 32 * w + 16 * nt + fl;
                    __builtin_nontemporal_store(acc[g][mt][nt][r],
                        &out[(size_t)row * (2 * D_FEAT) + col]);
                }
}

extern "C" void kernel_launch(void* const* d_in, const int* in_sizes, int n_in,
                              void* d_out, int out_size, void* d_ws, size_t ws_size,
                              hipStream_t stream) {
    const float* x      = (const float*)d_in[0];
    const float* adj_t  = (const float*)d_in[1];
    const float* adj_t2 = (const float*)d_in[2];
    float* out = (float*)d_out;
    unsigned short* xT = (unsigned short*)d_ws;   // 256*8192 bf16 = 4 MiB
    (void)in_sizes; (void)n_in; (void)out_size; (void)ws_size;

    // 1) transpose+convert x -> xT (bf16, [n][k])
    hipLaunchKernelGGL(xpose_kernel, dim3(N_TOT / 64, D_FEAT / 64), dim3(256), 0, stream, x, xT);
    // 2) fused dual GEMM: 256 m-tiles, both adjacency matrices per block
    hipLaunchKernelGGL(h2gcn_kernel, dim3(N_TOT / BM), dim3(512), 0, stream,
                       adj_t, adj_t2, xT, out);
}